// Round 1
// baseline (297.729 us; speedup 1.0000x reference)
//
#include <hip/hip_runtime.h>

// out[e, i, c] = sum_j inv[e, i, j] * conv[mesh[e, j], c]
// E = 2,000,000 elements, K = 4, C = 3.  N_NODES = 400,000.
//
// Ideal HBM traffic ~261 MB -> ~42 us at 6.3 TB/s achievable.
// v2 strategy:
//  - nt loads/stores for the single-use streams (mesh, inv, out) so the
//    4.8 MB conv gather table stays L2-resident (kills the ~121 MB over-fetch).
//  - pre-pad conv to (N,4) float4 in workspace: each gather = ONE aligned
//    16 B dwordx4 instead of 2-3 scattered sub-16B requests.
//  - 2 elements/thread (block-contiguous) for 2x memory-level parallelism
//    across the mesh->gather dependent chain.

typedef float v4f __attribute__((ext_vector_type(4)));
typedef int   v4i __attribute__((ext_vector_type(4)));

#define EPT 2

__global__ __launch_bounds__(256) void
pad_conv_kernel(const float* __restrict__ conv, float* __restrict__ convp, int n) {
    int v = blockIdx.x * blockDim.x + threadIdx.x;
    if (v >= n) return;
    const float* p = conv + 3 * (size_t)v;
    v4f q;
    q.x = p[0];
    q.y = p[1];
    q.z = p[2];
    q.w = 0.0f;
    // regular (cached) store: convp is immediately re-read by the main kernel
    *reinterpret_cast<v4f*>(convp + 4 * (size_t)v) = q;
}

__global__ __launch_bounds__(256) void
elem_matmul_v2(const float* __restrict__ convp,  // (N, 4) padded, 16B/vertex
               const int* __restrict__ mesh,
               const float* __restrict__ inv,
               float* __restrict__ out,
               int E) {
    const int base = blockIdx.x * (256 * EPT) + threadIdx.x;

    int  e[EPT];
    bool ok[EPT];
#pragma unroll
    for (int k = 0; k < EPT; ++k) {
        e[k] = base + 256 * k;       // consecutive lanes -> consecutive elements
        ok[k] = (e[k] < E);
    }

    // ---- issue all index loads first (independent; nt = don't pollute L2) ----
    v4i idx[EPT];
#pragma unroll
    for (int k = 0; k < EPT; ++k) {
        if (ok[k])
            idx[k] = __builtin_nontemporal_load(
                reinterpret_cast<const v4i*>(mesh) + (size_t)e[k]);
    }

    // ---- inverse matrices: 4x16B per element, streaming, nt ----
    v4f r0[EPT], r1[EPT], r2[EPT], r3[EPT];
#pragma unroll
    for (int k = 0; k < EPT; ++k) {
        if (ok[k]) {
            const v4f* ip = reinterpret_cast<const v4f*>(inv) + 4 * (size_t)e[k];
            r0[k] = __builtin_nontemporal_load(ip + 0);
            r1[k] = __builtin_nontemporal_load(ip + 1);
            r2[k] = __builtin_nontemporal_load(ip + 2);
            r3[k] = __builtin_nontemporal_load(ip + 3);
        }
    }

    // ---- gathers: one aligned dwordx4 per vertex, cached (L2-resident) ----
    v4f g[EPT][4];
#pragma unroll
    for (int k = 0; k < EPT; ++k) {
        if (ok[k]) {
            const int v0 = idx[k].x, v1 = idx[k].y, v2 = idx[k].z, v3 = idx[k].w;
            g[k][0] = *reinterpret_cast<const v4f*>(convp + 4 * (size_t)v0);
            g[k][1] = *reinterpret_cast<const v4f*>(convp + 4 * (size_t)v1);
            g[k][2] = *reinterpret_cast<const v4f*>(convp + 4 * (size_t)v2);
            g[k][3] = *reinterpret_cast<const v4f*>(convp + 4 * (size_t)v3);
        }
    }

    // ---- 48 FMAs per element + nt stores (write-once stream) ----
#pragma unroll
    for (int k = 0; k < EPT; ++k) {
        if (!ok[k]) continue;
        float o[4][3];
#pragma unroll
        for (int c = 0; c < 3; ++c) {
            o[0][c] = r0[k].x * g[k][0][c] + r0[k].y * g[k][1][c] +
                      r0[k].z * g[k][2][c] + r0[k].w * g[k][3][c];
            o[1][c] = r1[k].x * g[k][0][c] + r1[k].y * g[k][1][c] +
                      r1[k].z * g[k][2][c] + r1[k].w * g[k][3][c];
            o[2][c] = r2[k].x * g[k][0][c] + r2[k].y * g[k][1][c] +
                      r2[k].z * g[k][2][c] + r2[k].w * g[k][3][c];
            o[3][c] = r3[k].x * g[k][0][c] + r3[k].y * g[k][1][c] +
                      r3[k].z * g[k][2][c] + r3[k].w * g[k][3][c];
        }
        v4f s0 = {o[0][0], o[0][1], o[0][2], o[1][0]};
        v4f s1 = {o[1][1], o[1][2], o[2][0], o[2][1]};
        v4f s2 = {o[2][2], o[3][0], o[3][1], o[3][2]};
        v4f* op = reinterpret_cast<v4f*>(out + 12 * (size_t)e[k]);  // 48B-aligned base, 16B ok
        __builtin_nontemporal_store(s0, op + 0);
        __builtin_nontemporal_store(s1, op + 1);
        __builtin_nontemporal_store(s2, op + 2);
    }
}

// Fallback (no/undersized workspace): previous best kernel, unpadded gather.
__global__ __launch_bounds__(256) void
elem_matmul_fallback(const float* __restrict__ conv,
                     const int* __restrict__ mesh,
                     const float* __restrict__ inv,
                     float* __restrict__ out,
                     int E) {
    int e = blockIdx.x * blockDim.x + threadIdx.x;
    if (e >= E) return;
    const int4 idx = *reinterpret_cast<const int4*>(mesh + 4 * (size_t)e);
    const float4* ip = reinterpret_cast<const float4*>(inv + 16 * (size_t)e);
    const float4 r0 = ip[0], r1 = ip[1], r2 = ip[2], r3 = ip[3];
    const int vs[4] = {idx.x, idx.y, idx.z, idx.w};
    float g[4][3];
#pragma unroll
    for (int j = 0; j < 4; ++j) {
        const float* p = conv + 3 * (size_t)vs[j];
        g[j][0] = p[0]; g[j][1] = p[1]; g[j][2] = p[2];
    }
    float o[4][3];
#pragma unroll
    for (int c = 0; c < 3; ++c) {
        o[0][c] = r0.x * g[0][c] + r0.y * g[1][c] + r0.z * g[2][c] + r0.w * g[3][c];
        o[1][c] = r1.x * g[0][c] + r1.y * g[1][c] + r1.z * g[2][c] + r1.w * g[3][c];
        o[2][c] = r2.x * g[0][c] + r2.y * g[1][c] + r2.z * g[2][c] + r2.w * g[3][c];
        o[3][c] = r3.x * g[0][c] + r3.y * g[1][c] + r3.z * g[2][c] + r3.w * g[3][c];
    }
    float4* op = reinterpret_cast<float4*>(out + 12 * (size_t)e);
    op[0] = make_float4(o[0][0], o[0][1], o[0][2], o[1][0]);
    op[1] = make_float4(o[1][1], o[1][2], o[2][0], o[2][1]);
    op[2] = make_float4(o[2][2], o[3][0], o[3][1], o[3][2]);
}

extern "C" void kernel_launch(void* const* d_in, const int* in_sizes, int n_in,
                              void* d_out, int out_size, void* d_ws, size_t ws_size,
                              hipStream_t stream) {
    const float* conv = (const float*)d_in[0];   // (N, 3) f32
    const int* mesh = (const int*)d_in[1];       // (E, 4) i32
    const float* inv = (const float*)d_in[2];    // (E, 4, 4) f32
    float* out = (float*)d_out;                  // (E, 4, 3) f32

    const int E = in_sizes[1] / 4;
    const int n_nodes = in_sizes[0] / 3;
    const size_t pad_bytes = (size_t)n_nodes * 4 * sizeof(float);

    if (d_ws != nullptr && ws_size >= pad_bytes) {
        float* convp = (float*)d_ws;
        pad_conv_kernel<<<(n_nodes + 255) / 256, 256, 0, stream>>>(conv, convp, n_nodes);
        const int per_block = 256 * EPT;
        const int grid = (E + per_block - 1) / per_block;
        elem_matmul_v2<<<grid, 256, 0, stream>>>(convp, mesh, inv, out, E);
    } else {
        const int grid = (E + 255) / 256;
        elem_matmul_fallback<<<grid, 256, 0, stream>>>(conv, mesh, inv, out, E);
    }
}